// Round 14
// baseline (529.888 us; speedup 1.0000x reference)
//
#include <hip/hip_runtime.h>
#include <hip/hip_bf16.h>

#define NN   100000
#define NE   800000
#define DIN  512
#define DHID 512
#define DOUT 256
#define CAP  64        // max neighbors stored per node (Poisson(8): P(>64)≈0)

typedef short  s16x8 __attribute__((ext_vector_type(8)));
typedef float  f32x4 __attribute__((ext_vector_type(4)));

__device__ __forceinline__ float bf2f(unsigned short b) {
    union { unsigned u; float f; } c; c.u = ((unsigned)b) << 16; return c.f;
}
__device__ __forceinline__ unsigned short f2bf(float f) {
    union { float f; unsigned u; } c; c.f = f;
    unsigned u = c.u;
    u += 0x7FFFu + ((u >> 16) & 1u);   // round-to-nearest-even
    return (unsigned short)(u >> 16);
}
__device__ __forceinline__ unsigned cvtpk_bf16(float lo, float hi) {
    unsigned r;
    asm("v_cvt_pk_bf16_f32 %0, %1, %2" : "=v"(r) : "v"(lo), "v"(hi));
    return r;                                  // {bf16(lo), bf16(hi)} RNE
}

__device__ __forceinline__ void gload_lds16(const void* g, void* l) {
    __builtin_amdgcn_global_load_lds(
        (const __attribute__((address_space(1))) void*)g,
        (__attribute__((address_space(3))) void*)l, 16, 0, 0);
}

// ---------- adjacency build (fixed-capacity, no scan) ----------
__global__ void k_zero(int* cur) {
    int i = blockIdx.x * 256 + threadIdx.x;
    if (i < NN) cur[i] = 0;
}
__global__ void k_fill64(const int* __restrict__ src, const int* __restrict__ dst,
                         int* __restrict__ cur, int* __restrict__ col)
{
    int i = blockIdx.x * 256 + threadIdx.x;
    if (i < NE) {
        const int d = dst[i];
        const int slot = atomicAdd(&cur[d], 1);
        if (slot < CAP) col[(size_t)d * CAP + slot] = src[i];
    }
}

// W1[512][512] -> Wt1[512][512] bf16 ; W2[512][256] -> Wt2[256][512] bf16
__global__ __launch_bounds__(256) void k_wt_all(
    const float* __restrict__ W1, const float* __restrict__ W2,
    unsigned short* __restrict__ Wt1, unsigned short* __restrict__ Wt2)
{
    const int idx = blockIdx.x * 256 + threadIdx.x;
    if (idx < 512 * 512) {
        const int k = idx >> 9, n = idx & 511;
        Wt1[n * 512 + k] = f2bf(W1[idx]);
    } else {
        const int r = idx - 512 * 512;
        if (r < 512 * 256) {
            const int k = r >> 8, n = r & 255;
            Wt2[n * 512 + k] = f2bf(W2[r]);
        }
    }
}

// ---------- GEMM1 (reg-staged f32 A, one-iter A-prefetch, dynamic K-loop) ----
// A: global f32 -> regs (prefetched one K-step ahead) -> v_cvt_pk_bf16_f32 ->
// ds_write_b128 into the XOR-swizzled bf16 LDS layout (read side unchanged).
// B: global_load_lds. A-prefetch drains at the SAME vmcnt(0)+barrier as B's
// gloads. NOTE: K-loop deliberately NOT unrolled (r13: full unroll wrecked
// scheduling, VALUBusy 18->10%). 128x128 tile, 4 waves, BK=32, XCD swizzle.
__global__ __launch_bounds__(256) void k_gemm1_rs(
    const float* __restrict__ A,            // [M][512] f32
    const unsigned short* __restrict__ Wt,  // [512][512] bf16
    const int* __restrict__ cur,
    unsigned short* __restrict__ Hb,        // [M][512] bf16 (h*dinv[m])
    int M)
{
    constexpr int K = 512, NC = 512, GN = NC / 128;
    __shared__ __align__(16) unsigned short As[128 * 32];
    __shared__ __align__(16) unsigned short Bs[128 * 32];

    const int GM  = (M + 127) >> 7;
    const int nwg = GM * GN;
    const int bid = blockIdx.x;
    const int q = nwg >> 3, r = nwg & 7;
    const int xcd = bid & 7, pos = bid >> 3;
    const int sbid = (xcd < r ? xcd * (q + 1) : r * (q + 1) + (xcd - r) * q) + pos;
    const int bm = (sbid / GN) * 128;
    const int bn = (sbid % GN) * 128;

    const int t    = threadIdx.x;
    const int lane = t & 63;
    const int wid  = t >> 6;
    const int wr = wid >> 1, wc = wid & 1;

    // A staging: thread t owns chunks c0=t and c1=t+256 (chunk = 8 elems)
    const int arow0 = t >> 2,          acp0 = t & 3;
    const int arow1 = (t + 256) >> 2,  acp1 = t & 3;   // (t+256)&3 == t&3
    int gr0 = bm + arow0; if (gr0 >= M) gr0 = M - 1;
    int gr1 = bm + arow1; if (gr1 >= M) gr1 = M - 1;
    const float* ga0 = A + (size_t)gr0 * K + acp0 * 8;
    const float* ga1 = A + (size_t)gr1 * K + acp1 * 8;
    unsigned short* wa0 = &As[arow0 * 32 + (acp0 ^ ((arow0 >> 1) & 3)) * 8];
    unsigned short* wa1 = &As[arow1 * 32 + (acp1 ^ ((arow1 >> 1) & 3)) * 8];

    f32x4 acc[4][4];
    #pragma unroll
    for (int i = 0; i < 4; ++i)
        #pragma unroll
        for (int j = 0; j < 4; ++j)
            acc[i][j] = (f32x4){0.f, 0.f, 0.f, 0.f};

    const int r16 = lane & 15;
    const int kc  = lane >> 4;

    // ---- prologue: A regs for k0 = 0 ----
    f32x4 c00 = *reinterpret_cast<const f32x4*>(ga0);
    f32x4 c01 = *reinterpret_cast<const f32x4*>(ga0 + 4);
    f32x4 c10 = *reinterpret_cast<const f32x4*>(ga1);
    f32x4 c11 = *reinterpret_cast<const f32x4*>(ga1 + 4);

    for (int k0 = 0; k0 < K; k0 += 32) {      // dynamic loop — do not unroll
        // ---- issue B gload_lds for tile k0 ----
        #pragma unroll
        for (int i = 0; i < 2; ++i) {
            const int c   = i * 256 + t;
            const int row = c >> 2;
            const int cp  = c & 3;
            const int sc  = cp ^ ((row >> 1) & 3);
            gload_lds16(Wt + (size_t)(bn + row) * K + k0 + sc * 8,
                        &Bs[(size_t)(i * 256 + wid * 64) * 8]);
        }
        // ---- issue A prefetch for tile k0+32 ----
        f32x4 n00, n01, n10, n11;
        if (k0 + 32 < K) {
            n00 = *reinterpret_cast<const f32x4*>(ga0 + k0 + 32);
            n01 = *reinterpret_cast<const f32x4*>(ga0 + k0 + 36);
            n10 = *reinterpret_cast<const f32x4*>(ga1 + k0 + 32);
            n11 = *reinterpret_cast<const f32x4*>(ga1 + k0 + 36);
        }
        // ---- convert current A regs + ds_write (swizzled, bank-balanced) ----
        uint4 p0, p1;
        p0.x = cvtpk_bf16(c00[0], c00[1]);  p0.y = cvtpk_bf16(c00[2], c00[3]);
        p0.z = cvtpk_bf16(c01[0], c01[1]);  p0.w = cvtpk_bf16(c01[2], c01[3]);
        p1.x = cvtpk_bf16(c10[0], c10[1]);  p1.y = cvtpk_bf16(c10[2], c10[3]);
        p1.z = cvtpk_bf16(c11[0], c11[1]);  p1.w = cvtpk_bf16(c11[2], c11[3]);
        *reinterpret_cast<uint4*>(wa0) = p0;
        *reinterpret_cast<uint4*>(wa1) = p1;
        __syncthreads();     // As written; B gloads + A prefetch drain together

        s16x8 af[4], bf[4];
        #pragma unroll
        for (int i = 0; i < 4; ++i) {
            const int ra = wr * 64 + i * 16 + r16;
            af[i] = *reinterpret_cast<const s16x8*>(
                &As[ra * 32 + ((kc ^ ((ra >> 1) & 3)) * 8)]);
            const int rb = wc * 64 + i * 16 + r16;
            bf[i] = *reinterpret_cast<const s16x8*>(
                &Bs[rb * 32 + ((kc ^ ((rb >> 1) & 3)) * 8)]);
        }
        #pragma unroll
        for (int i = 0; i < 4; ++i)
            #pragma unroll
            for (int j = 0; j < 4; ++j)
                acc[i][j] = __builtin_amdgcn_mfma_f32_16x16x32_bf16(
                    af[i], bf[j], acc[i][j], 0, 0, 0);
        __syncthreads();     // reads done before next iter's writes

        c00 = n00; c01 = n01; c10 = n10; c11 = n11;
    }

    #pragma unroll
    for (int i = 0; i < 4; ++i) {
        #pragma unroll
        for (int r2 = 0; r2 < 4; ++r2) {
            const int m = bm + wr * 64 + i * 16 + (lane >> 4) * 4 + r2;
            if (m >= M) continue;
            const float s = rsqrtf((float)cur[m] + 1.0f);
            #pragma unroll
            for (int j = 0; j < 4; ++j) {
                const int n = bn + wc * 64 + j * 16 + (lane & 15);
                Hb[(size_t)m * NC + n] = f2bf(acc[i][j][r2] * s);
            }
        }
    }
}

// ---------- GEMM2 (bf16 A via gload_lds): C[M][NC] = A[M][512] x Wt[NC][512]^T ---
template<int NC>
__global__ __launch_bounds__(256) void k_mfma_gemm(
    const unsigned short* __restrict__ A,   // [M][512] bf16
    const unsigned short* __restrict__ Wt,  // [NC][512] bf16
    const int* __restrict__ cur,
    unsigned short* __restrict__ Hb,        // [M][NC] bf16  (h*dinv[m])
    int M)
{
    constexpr int K  = 512;
    constexpr int GN = NC / 128;
    __shared__ __align__(16) unsigned short As[128 * 32];
    __shared__ __align__(16) unsigned short Bs[128 * 32];

    const int GM  = (M + 127) >> 7;
    const int nwg = GM * GN;
    const int bid = blockIdx.x;
    const int q = nwg >> 3, r = nwg & 7;
    const int xcd = bid & 7, pos = bid >> 3;
    const int sbid = (xcd < r ? xcd * (q + 1) : r * (q + 1) + (xcd - r) * q) + pos;
    const int bm = (sbid / GN) * 128;
    const int bn = (sbid % GN) * 128;

    const int t    = threadIdx.x;
    const int lane = t & 63;
    const int wid  = t >> 6;
    const int wr = wid >> 1, wc = wid & 1;

    f32x4 acc[4][4];
    #pragma unroll
    for (int i = 0; i < 4; ++i)
        #pragma unroll
        for (int j = 0; j < 4; ++j)
            acc[i][j] = (f32x4){0.f, 0.f, 0.f, 0.f};

    const int r16 = lane & 15;
    const int kc  = lane >> 4;

    for (int k0 = 0; k0 < K; k0 += 32) {
        #pragma unroll
        for (int i = 0; i < 2; ++i) {
            const int c   = i * 256 + t;
            const int row = c >> 2;
            const int cp  = c & 3;
            const int sc  = cp ^ ((row >> 1) & 3);
            const int gr  = (bm + row < M) ? bm + row : M - 1;
            gload_lds16(A  + (size_t)gr * K + k0 + sc * 8,
                        &As[(size_t)(i * 256 + wid * 64) * 8]);
            gload_lds16(Wt + (size_t)(bn + row) * K + k0 + sc * 8,
                        &Bs[(size_t)(i * 256 + wid * 64) * 8]);
        }
        __syncthreads();

        s16x8 af[4], bf[4];
        #pragma unroll
        for (int i = 0; i < 4; ++i) {
            const int ra = wr * 64 + i * 16 + r16;
            af[i] = *reinterpret_cast<const s16x8*>(
                &As[ra * 32 + ((kc ^ ((ra >> 1) & 3)) * 8)]);
            const int rb = wc * 64 + i * 16 + r16;
            bf[i] = *reinterpret_cast<const s16x8*>(
                &Bs[rb * 32 + ((kc ^ ((rb >> 1) & 3)) * 8)]);
        }
        #pragma unroll
        for (int i = 0; i < 4; ++i)
            #pragma unroll
            for (int j = 0; j < 4; ++j)
                acc[i][j] = __builtin_amdgcn_mfma_f32_16x16x32_bf16(
                    af[i], bf[j], acc[i][j], 0, 0, 0);
        __syncthreads();
    }

    #pragma unroll
    for (int i = 0; i < 4; ++i) {
        #pragma unroll
        for (int r2 = 0; r2 < 4; ++r2) {
            const int m = bm + wr * 64 + i * 16 + (lane >> 4) * 4 + r2;
            if (m >= M) continue;
            const float s = rsqrtf((float)cur[m] + 1.0f);
            #pragma unroll
            for (int j = 0; j < 4; ++j) {
                const int n = bn + wc * 64 + j * 16 + (lane & 15);
                Hb[(size_t)m * NC + n] = f2bf(acc[i][j][r2] * s);
            }
        }
    }
}

// ---------- pull, D=512: one wave per node, fused bias+relu, bf16 out ----------
__device__ __forceinline__ void add8(const uint4 u, float* a) {
    a[0] += bf2f((unsigned short)(u.x));  a[1] += bf2f((unsigned short)(u.x >> 16));
    a[2] += bf2f((unsigned short)(u.y));  a[3] += bf2f((unsigned short)(u.y >> 16));
    a[4] += bf2f((unsigned short)(u.z));  a[5] += bf2f((unsigned short)(u.z >> 16));
    a[6] += bf2f((unsigned short)(u.w));  a[7] += bf2f((unsigned short)(u.w >> 16));
}

__global__ __launch_bounds__(256) void k_pull512(
    const int* __restrict__ cur, const int* __restrict__ col,
    const unsigned short* __restrict__ H,
    const float* __restrict__ bias, unsigned short* __restrict__ Out)
{
    const int node = blockIdx.x * 4 + (threadIdx.x >> 6);
    if (node >= NN) return;
    const int lane = threadIdx.x & 63;

    float a[8] = {0.f, 0.f, 0.f, 0.f, 0.f, 0.f, 0.f, 0.f};
    add8(*reinterpret_cast<const uint4*>(H + (size_t)node * DHID + lane * 8), a);

    const int deg0 = cur[node];
    const int deg  = deg0 < CAP ? deg0 : CAP;
    const int* cl = col + (size_t)node * CAP;
    for (int e = 0; e < deg; ++e) {
        const int s = cl[e];
        add8(*reinterpret_cast<const uint4*>(H + (size_t)s * DHID + lane * 8), a);
    }

    const float sc = rsqrtf((float)deg0 + 1.0f);
    unsigned o[4];
    #pragma unroll
    for (int p = 0; p < 4; ++p) {
        float v0 = a[2 * p]     * sc + bias[lane * 8 + 2 * p];
        float v1 = a[2 * p + 1] * sc + bias[lane * 8 + 2 * p + 1];
        v0 = v0 > 0.f ? v0 : 0.f;
        v1 = v1 > 0.f ? v1 : 0.f;
        o[p] = (unsigned)f2bf(v0) | ((unsigned)f2bf(v1) << 16);
    }
    uint4 r = {o[0], o[1], o[2], o[3]};
    *reinterpret_cast<uint4*>(Out + (size_t)node * DHID + lane * 8) = r;
}

// ---------- pull, D=256: fused bias+log_softmax, f32 out ----------
__device__ __forceinline__ void add4(const uint2 u, float* a) {
    a[0] += bf2f((unsigned short)(u.x));  a[1] += bf2f((unsigned short)(u.x >> 16));
    a[2] += bf2f((unsigned short)(u.y));  a[3] += bf2f((unsigned short)(u.y >> 16));
}

__global__ __launch_bounds__(256) void k_pull256_lsm(
    const int* __restrict__ cur, const int* __restrict__ col,
    const unsigned short* __restrict__ H,
    const float* __restrict__ b2, float* __restrict__ out)
{
    const int node = blockIdx.x * 4 + (threadIdx.x >> 6);
    if (node >= NN) return;
    const int lane = threadIdx.x & 63;

    float a[4] = {0.f, 0.f, 0.f, 0.f};
    add4(*reinterpret_cast<const uint2*>(H + (size_t)node * DOUT + lane * 4), a);

    const int deg0 = cur[node];
    const int deg  = deg0 < CAP ? deg0 : CAP;
    const int* cl = col + (size_t)node * CAP;
    for (int e = 0; e < deg; ++e) {
        const int s = cl[e];
        add4(*reinterpret_cast<const uint2*>(H + (size_t)s * DOUT + lane * 4), a);
    }

    const float sc = rsqrtf((float)deg0 + 1.0f);
    float v0 = a[0] * sc + b2[lane * 4 + 0];
    float v1 = a[1] * sc + b2[lane * 4 + 1];
    float v2 = a[2] * sc + b2[lane * 4 + 2];
    float v3 = a[3] * sc + b2[lane * 4 + 3];

    float m = fmaxf(fmaxf(v0, v1), fmaxf(v2, v3));
    #pragma unroll
    for (int off = 32; off > 0; off >>= 1) m = fmaxf(m, __shfl_xor(m, off));
    float s = expf(v0 - m) + expf(v1 - m) + expf(v2 - m) + expf(v3 - m);
    #pragma unroll
    for (int off = 32; off > 0; off >>= 1) s += __shfl_xor(s, off);
    const float lse = m + logf(s);

    float4 rr = {v0 - lse, v1 - lse, v2 - lse, v3 - lse};
    *reinterpret_cast<float4*>(out + (size_t)node * DOUT + lane * 4) = rr;
}

extern "C" void kernel_launch(void* const* d_in, const int* in_sizes, int n_in,
                              void* d_out, int out_size, void* d_ws, size_t ws_size,
                              hipStream_t stream)
{
    const float* x  = (const float*)d_in[0];
    const int*   ei = (const int*)d_in[1];
    const float* W1 = (const float*)d_in[2];
    const float* b1 = (const float*)d_in[3];
    const float* W2 = (const float*)d_in[4];
    const float* b2 = (const float*)d_in[5];
    float* out = (float*)d_out;

    const int* src = ei;        // edge_index[0]
    const int* dst = ei + NE;   // edge_index[1]

    // workspace (high-water ~247 MiB):
    //   0.0MiB  cur   int[NN]
    //   1.0MiB  col   int[NN*64]             (25.6MB)
    //   28MiB   Wt1   bf16[512][512]
    //   29MiB   Wt2   bf16[256][512]
    //   32MiB   P: Hr bf16[NN][512]
    //   144MiB  Q: H1 bf16[NN][512] -> reused as H2 bf16[NN][256]
    char* ws = (char*)d_ws;
    int*   cur  = (int*)(ws);
    int*   col  = (int*)(ws + (size_t)(1 << 20));
    unsigned short* Wt1 = (unsigned short*)(ws + (size_t)28 * (1 << 20));
    unsigned short* Wt2 = (unsigned short*)(ws + (size_t)29 * (1 << 20));
    unsigned short* Hr  = (unsigned short*)(ws + (size_t)32  * (1 << 20));
    unsigned short* Q   = (unsigned short*)(ws + (size_t)144 * (1 << 20));
    unsigned short* H1 = Q, * H2 = Q;

    const int g256n = (NN + 255) / 256;
    const int g256e = (NE + 255) / 256;

    k_zero  <<<g256n, 256, 0, stream>>>(cur);
    k_fill64<<<g256e, 256, 0, stream>>>(src, dst, cur, col);
    k_wt_all<<<(512 * 768 + 255) / 256, 256, 0, stream>>>(W1, W2, Wt1, Wt2);

    const int GM = (NN + 127) / 128;                 // 782
    k_gemm1_rs<<<GM * (DHID / 128), 256, 0, stream>>>(x, Wt1, cur, H1, NN);
    k_pull512<<<(NN + 3) / 4, 256, 0, stream>>>(cur, col, H1, b1, Hr);

    k_mfma_gemm<DOUT><<<GM * (DOUT / 128), 256, 0, stream>>>(Hr, Wt2, cur, H2, NN);
    k_pull256_lsm<<<(NN + 3) / 4, 256, 0, stream>>>(cur, col, H2, b2, out);
}

// Round 15
// 493.846 us; speedup vs baseline: 1.0730x; 1.0730x over previous
//
#include <hip/hip_runtime.h>
#include <hip/hip_bf16.h>

#define NN   100000
#define NE   800000
#define DIN  512
#define DHID 512
#define DOUT 256
#define CAP  64        // max neighbors stored per node (Poisson(8): P(>64)≈0)

typedef short  s16x8 __attribute__((ext_vector_type(8)));
typedef float  f32x4 __attribute__((ext_vector_type(4)));

__device__ __forceinline__ float bf2f(unsigned short b) {
    union { unsigned u; float f; } c; c.u = ((unsigned)b) << 16; return c.f;
}
__device__ __forceinline__ unsigned short f2bf(float f) {
    union { float f; unsigned u; } c; c.f = f;
    unsigned u = c.u;
    u += 0x7FFFu + ((u >> 16) & 1u);   // round-to-nearest-even
    return (unsigned short)(u >> 16);
}
__device__ __forceinline__ unsigned cvtpk_bf16(float lo, float hi) {
    unsigned r;
    asm("v_cvt_pk_bf16_f32 %0, %1, %2" : "=v"(r) : "v"(lo), "v"(hi));
    return r;                                  // {bf16(lo), bf16(hi)} RNE
}

__device__ __forceinline__ void gload_lds16(const void* g, void* l) {
    __builtin_amdgcn_global_load_lds(
        (const __attribute__((address_space(1))) void*)g,
        (__attribute__((address_space(3))) void*)l, 16, 0, 0);
}

// ---------- adjacency build (fixed-capacity, no scan) ----------
__global__ void k_zero(int* cur) {
    int i = blockIdx.x * 256 + threadIdx.x;
    if (i < NN) cur[i] = 0;
}
__global__ void k_fill64(const int* __restrict__ src, const int* __restrict__ dst,
                         int* __restrict__ cur, int* __restrict__ col)
{
    int i = blockIdx.x * 256 + threadIdx.x;
    if (i < NE) {
        const int d = dst[i];
        const int slot = atomicAdd(&cur[d], 1);
        if (slot < CAP) col[(size_t)d * CAP + slot] = src[i];
    }
}

// W1[512][512] -> Wt1[512][512] bf16 ; W2[512][256] -> Wt2[256][512] bf16
__global__ __launch_bounds__(256) void k_wt_all(
    const float* __restrict__ W1, const float* __restrict__ W2,
    unsigned short* __restrict__ Wt1, unsigned short* __restrict__ Wt2)
{
    const int idx = blockIdx.x * 256 + threadIdx.x;
    if (idx < 512 * 512) {
        const int k = idx >> 9, n = idx & 511;
        Wt1[n * 512 + k] = f2bf(W1[idx]);
    } else {
        const int r = idx - 512 * 512;
        if (r < 512 * 256) {
            const int k = r >> 8, n = r & 255;
            Wt2[n * 512 + k] = f2bf(W2[r]);
        }
    }
}

// ---------- GEMM1 (reg-staged f32 A): C[M][512] = A_f32[M][512] x Wt[512][512]^T --
// A: global f32 -> regs -> v_cvt_pk_bf16_f32 -> ds_write_b128 into the SAME
// XOR-swizzled bf16 LDS layout the proven kernel reads (read side unchanged).
// B: global_load_lds as before. 128x128 tile, 4 waves, BK=32, XCD swizzle.
// NOTE (r13/r14): K-loop must stay dynamic (full unroll wrecks scheduling) and
// NO register prefetch (VGPR 76->92 drops occupancy 30->21%, net loss).
__global__ __launch_bounds__(256) void k_gemm1_rs(
    const float* __restrict__ A,            // [M][512] f32
    const unsigned short* __restrict__ Wt,  // [512][512] bf16
    const int* __restrict__ cur,
    unsigned short* __restrict__ Hb,        // [M][512] bf16 (h*dinv[m])
    int M)
{
    constexpr int K = 512, NC = 512, GN = NC / 128;
    __shared__ __align__(16) unsigned short As[128 * 32];
    __shared__ __align__(16) unsigned short Bs[128 * 32];

    const int GM  = (M + 127) >> 7;
    const int nwg = GM * GN;
    const int bid = blockIdx.x;
    const int q = nwg >> 3, r = nwg & 7;
    const int xcd = bid & 7, pos = bid >> 3;
    const int sbid = (xcd < r ? xcd * (q + 1) : r * (q + 1) + (xcd - r) * q) + pos;
    const int bm = (sbid / GN) * 128;
    const int bn = (sbid % GN) * 128;

    const int t    = threadIdx.x;
    const int lane = t & 63;
    const int wid  = t >> 6;
    const int wr = wid >> 1, wc = wid & 1;

    // A staging: thread t owns chunks c0=t and c1=t+256 (chunk = 8 elems)
    const int arow0 = t >> 2,          acp0 = t & 3;
    const int arow1 = (t + 256) >> 2,  acp1 = t & 3;   // (t+256)&3 == t&3
    int gr0 = bm + arow0; if (gr0 >= M) gr0 = M - 1;
    int gr1 = bm + arow1; if (gr1 >= M) gr1 = M - 1;
    const float* ga0 = A + (size_t)gr0 * K + acp0 * 8;
    const float* ga1 = A + (size_t)gr1 * K + acp1 * 8;
    unsigned short* wa0 = &As[arow0 * 32 + (acp0 ^ ((arow0 >> 1) & 3)) * 8];
    unsigned short* wa1 = &As[arow1 * 32 + (acp1 ^ ((arow1 >> 1) & 3)) * 8];

    f32x4 acc[4][4];
    #pragma unroll
    for (int i = 0; i < 4; ++i)
        #pragma unroll
        for (int j = 0; j < 4; ++j)
            acc[i][j] = (f32x4){0.f, 0.f, 0.f, 0.f};

    const int r16 = lane & 15;
    const int kc  = lane >> 4;

    for (int k0 = 0; k0 < K; k0 += 32) {
        // ---- issue A f32 loads (4x dwordx4) and B gload_lds ----
        const f32x4 a00 = *reinterpret_cast<const f32x4*>(ga0 + k0);
        const f32x4 a01 = *reinterpret_cast<const f32x4*>(ga0 + k0 + 4);
        const f32x4 a10 = *reinterpret_cast<const f32x4*>(ga1 + k0);
        const f32x4 a11 = *reinterpret_cast<const f32x4*>(ga1 + k0 + 4);
        #pragma unroll
        for (int i = 0; i < 2; ++i) {
            const int c   = i * 256 + t;
            const int row = c >> 2;
            const int cp  = c & 3;
            const int sc  = cp ^ ((row >> 1) & 3);
            gload_lds16(Wt + (size_t)(bn + row) * K + k0 + sc * 8,
                        &Bs[(size_t)(i * 256 + wid * 64) * 8]);
        }
        // ---- convert + ds_write (swizzled slots; bank-balanced) ----
        uint4 p0, p1;
        p0.x = cvtpk_bf16(a00[0], a00[1]);  p0.y = cvtpk_bf16(a00[2], a00[3]);
        p0.z = cvtpk_bf16(a01[0], a01[1]);  p0.w = cvtpk_bf16(a01[2], a01[3]);
        p1.x = cvtpk_bf16(a10[0], a10[1]);  p1.y = cvtpk_bf16(a10[2], a10[3]);
        p1.z = cvtpk_bf16(a11[0], a11[1]);  p1.w = cvtpk_bf16(a11[2], a11[3]);
        *reinterpret_cast<uint4*>(wa0) = p0;
        *reinterpret_cast<uint4*>(wa1) = p1;
        __syncthreads();     // As written, Bs gload drained

        s16x8 af[4], bf[4];
        #pragma unroll
        for (int i = 0; i < 4; ++i) {
            const int ra = wr * 64 + i * 16 + r16;
            af[i] = *reinterpret_cast<const s16x8*>(
                &As[ra * 32 + ((kc ^ ((ra >> 1) & 3)) * 8)]);
            const int rb = wc * 64 + i * 16 + r16;
            bf[i] = *reinterpret_cast<const s16x8*>(
                &Bs[rb * 32 + ((kc ^ ((rb >> 1) & 3)) * 8)]);
        }
        #pragma unroll
        for (int i = 0; i < 4; ++i)
            #pragma unroll
            for (int j = 0; j < 4; ++j)
                acc[i][j] = __builtin_amdgcn_mfma_f32_16x16x32_bf16(
                    af[i], bf[j], acc[i][j], 0, 0, 0);
        __syncthreads();     // reads done before next iter's writes
    }

    #pragma unroll
    for (int i = 0; i < 4; ++i) {
        #pragma unroll
        for (int r2 = 0; r2 < 4; ++r2) {
            const int m = bm + wr * 64 + i * 16 + (lane >> 4) * 4 + r2;
            if (m >= M) continue;
            const float s = rsqrtf((float)cur[m] + 1.0f);
            #pragma unroll
            for (int j = 0; j < 4; ++j) {
                const int n = bn + wc * 64 + j * 16 + (lane & 15);
                Hb[(size_t)m * NC + n] = f2bf(acc[i][j][r2] * s);
            }
        }
    }
}

// ---------- GEMM2 (bf16 A via gload_lds): C[M][NC] = A[M][512] x Wt[NC][512]^T ---
template<int NC>
__global__ __launch_bounds__(256) void k_mfma_gemm(
    const unsigned short* __restrict__ A,   // [M][512] bf16
    const unsigned short* __restrict__ Wt,  // [NC][512] bf16
    const int* __restrict__ cur,
    unsigned short* __restrict__ Hb,        // [M][NC] bf16  (h*dinv[m])
    int M)
{
    constexpr int K  = 512;
    constexpr int GN = NC / 128;
    __shared__ __align__(16) unsigned short As[128 * 32];
    __shared__ __align__(16) unsigned short Bs[128 * 32];

    const int GM  = (M + 127) >> 7;
    const int nwg = GM * GN;
    const int bid = blockIdx.x;
    const int q = nwg >> 3, r = nwg & 7;
    const int xcd = bid & 7, pos = bid >> 3;
    const int sbid = (xcd < r ? xcd * (q + 1) : r * (q + 1) + (xcd - r) * q) + pos;
    const int bm = (sbid / GN) * 128;
    const int bn = (sbid % GN) * 128;

    const int t    = threadIdx.x;
    const int lane = t & 63;
    const int wid  = t >> 6;
    const int wr = wid >> 1, wc = wid & 1;

    f32x4 acc[4][4];
    #pragma unroll
    for (int i = 0; i < 4; ++i)
        #pragma unroll
        for (int j = 0; j < 4; ++j)
            acc[i][j] = (f32x4){0.f, 0.f, 0.f, 0.f};

    const int r16 = lane & 15;
    const int kc  = lane >> 4;

    for (int k0 = 0; k0 < K; k0 += 32) {
        #pragma unroll
        for (int i = 0; i < 2; ++i) {
            const int c   = i * 256 + t;
            const int row = c >> 2;
            const int cp  = c & 3;
            const int sc  = cp ^ ((row >> 1) & 3);
            const int gr  = (bm + row < M) ? bm + row : M - 1;
            gload_lds16(A  + (size_t)gr * K + k0 + sc * 8,
                        &As[(size_t)(i * 256 + wid * 64) * 8]);
            gload_lds16(Wt + (size_t)(bn + row) * K + k0 + sc * 8,
                        &Bs[(size_t)(i * 256 + wid * 64) * 8]);
        }
        __syncthreads();

        s16x8 af[4], bf[4];
        #pragma unroll
        for (int i = 0; i < 4; ++i) {
            const int ra = wr * 64 + i * 16 + r16;
            af[i] = *reinterpret_cast<const s16x8*>(
                &As[ra * 32 + ((kc ^ ((ra >> 1) & 3)) * 8)]);
            const int rb = wc * 64 + i * 16 + r16;
            bf[i] = *reinterpret_cast<const s16x8*>(
                &Bs[rb * 32 + ((kc ^ ((rb >> 1) & 3)) * 8)]);
        }
        #pragma unroll
        for (int i = 0; i < 4; ++i)
            #pragma unroll
            for (int j = 0; j < 4; ++j)
                acc[i][j] = __builtin_amdgcn_mfma_f32_16x16x32_bf16(
                    af[i], bf[j], acc[i][j], 0, 0, 0);
        __syncthreads();
    }

    #pragma unroll
    for (int i = 0; i < 4; ++i) {
        #pragma unroll
        for (int r2 = 0; r2 < 4; ++r2) {
            const int m = bm + wr * 64 + i * 16 + (lane >> 4) * 4 + r2;
            if (m >= M) continue;
            const float s = rsqrtf((float)cur[m] + 1.0f);
            #pragma unroll
            for (int j = 0; j < 4; ++j) {
                const int n = bn + wc * 64 + j * 16 + (lane & 15);
                Hb[(size_t)m * NC + n] = f2bf(acc[i][j][r2] * s);
            }
        }
    }
}

// ---------- pull, D=512: one wave per node, fused bias+relu, bf16 out ----------
__device__ __forceinline__ void add8(const uint4 u, float* a) {
    a[0] += bf2f((unsigned short)(u.x));  a[1] += bf2f((unsigned short)(u.x >> 16));
    a[2] += bf2f((unsigned short)(u.y));  a[3] += bf2f((unsigned short)(u.y >> 16));
    a[4] += bf2f((unsigned short)(u.z));  a[5] += bf2f((unsigned short)(u.z >> 16));
    a[6] += bf2f((unsigned short)(u.w));  a[7] += bf2f((unsigned short)(u.w >> 16));
}

__global__ __launch_bounds__(256) void k_pull512(
    const int* __restrict__ cur, const int* __restrict__ col,
    const unsigned short* __restrict__ H,
    const float* __restrict__ bias, unsigned short* __restrict__ Out)
{
    const int node = blockIdx.x * 4 + (threadIdx.x >> 6);
    if (node >= NN) return;
    const int lane = threadIdx.x & 63;

    float a[8] = {0.f, 0.f, 0.f, 0.f, 0.f, 0.f, 0.f, 0.f};
    add8(*reinterpret_cast<const uint4*>(H + (size_t)node * DHID + lane * 8), a);

    const int deg0 = cur[node];
    const int deg  = deg0 < CAP ? deg0 : CAP;
    const int* cl = col + (size_t)node * CAP;
    for (int e = 0; e < deg; ++e) {
        const int s = cl[e];
        add8(*reinterpret_cast<const uint4*>(H + (size_t)s * DHID + lane * 8), a);
    }

    const float sc = rsqrtf((float)deg0 + 1.0f);
    unsigned o[4];
    #pragma unroll
    for (int p = 0; p < 4; ++p) {
        float v0 = a[2 * p]     * sc + bias[lane * 8 + 2 * p];
        float v1 = a[2 * p + 1] * sc + bias[lane * 8 + 2 * p + 1];
        v0 = v0 > 0.f ? v0 : 0.f;
        v1 = v1 > 0.f ? v1 : 0.f;
        o[p] = (unsigned)f2bf(v0) | ((unsigned)f2bf(v1) << 16);
    }
    uint4 r = {o[0], o[1], o[2], o[3]};
    *reinterpret_cast<uint4*>(Out + (size_t)node * DHID + lane * 8) = r;
}

// ---------- pull, D=256: fused bias+log_softmax, f32 out ----------
__device__ __forceinline__ void add4(const uint2 u, float* a) {
    a[0] += bf2f((unsigned short)(u.x));  a[1] += bf2f((unsigned short)(u.x >> 16));
    a[2] += bf2f((unsigned short)(u.y));  a[3] += bf2f((unsigned short)(u.y >> 16));
}

__global__ __launch_bounds__(256) void k_pull256_lsm(
    const int* __restrict__ cur, const int* __restrict__ col,
    const unsigned short* __restrict__ H,
    const float* __restrict__ b2, float* __restrict__ out)
{
    const int node = blockIdx.x * 4 + (threadIdx.x >> 6);
    if (node >= NN) return;
    const int lane = threadIdx.x & 63;

    float a[4] = {0.f, 0.f, 0.f, 0.f};
    add4(*reinterpret_cast<const uint2*>(H + (size_t)node * DOUT + lane * 4), a);

    const int deg0 = cur[node];
    const int deg  = deg0 < CAP ? deg0 : CAP;
    const int* cl = col + (size_t)node * CAP;
    for (int e = 0; e < deg; ++e) {
        const int s = cl[e];
        add4(*reinterpret_cast<const uint2*>(H + (size_t)s * DOUT + lane * 4), a);
    }

    const float sc = rsqrtf((float)deg0 + 1.0f);
    float v0 = a[0] * sc + b2[lane * 4 + 0];
    float v1 = a[1] * sc + b2[lane * 4 + 1];
    float v2 = a[2] * sc + b2[lane * 4 + 2];
    float v3 = a[3] * sc + b2[lane * 4 + 3];

    float m = fmaxf(fmaxf(v0, v1), fmaxf(v2, v3));
    #pragma unroll
    for (int off = 32; off > 0; off >>= 1) m = fmaxf(m, __shfl_xor(m, off));
    float s = expf(v0 - m) + expf(v1 - m) + expf(v2 - m) + expf(v3 - m);
    #pragma unroll
    for (int off = 32; off > 0; off >>= 1) s += __shfl_xor(s, off);
    const float lse = m + logf(s);

    float4 rr = {v0 - lse, v1 - lse, v2 - lse, v3 - lse};
    *reinterpret_cast<float4*>(out + (size_t)node * DOUT + lane * 4) = rr;
}

extern "C" void kernel_launch(void* const* d_in, const int* in_sizes, int n_in,
                              void* d_out, int out_size, void* d_ws, size_t ws_size,
                              hipStream_t stream)
{
    const float* x  = (const float*)d_in[0];
    const int*   ei = (const int*)d_in[1];
    const float* W1 = (const float*)d_in[2];
    const float* b1 = (const float*)d_in[3];
    const float* W2 = (const float*)d_in[4];
    const float* b2 = (const float*)d_in[5];
    float* out = (float*)d_out;

    const int* src = ei;        // edge_index[0]
    const int* dst = ei + NE;   // edge_index[1]

    // workspace (high-water ~247 MiB):
    //   0.0MiB  cur   int[NN]
    //   1.0MiB  col   int[NN*64]             (25.6MB)
    //   28MiB   Wt1   bf16[512][512]
    //   29MiB   Wt2   bf16[256][512]
    //   32MiB   P: Hr bf16[NN][512]
    //   144MiB  Q: H1 bf16[NN][512] -> reused as H2 bf16[NN][256]
    char* ws = (char*)d_ws;
    int*   cur  = (int*)(ws);
    int*   col  = (int*)(ws + (size_t)(1 << 20));
    unsigned short* Wt1 = (unsigned short*)(ws + (size_t)28 * (1 << 20));
    unsigned short* Wt2 = (unsigned short*)(ws + (size_t)29 * (1 << 20));
    unsigned short* Hr  = (unsigned short*)(ws + (size_t)32  * (1 << 20));
    unsigned short* Q   = (unsigned short*)(ws + (size_t)144 * (1 << 20));
    unsigned short* H1 = Q, * H2 = Q;

    const int g256n = (NN + 255) / 256;
    const int g256e = (NE + 255) / 256;

    k_zero  <<<g256n, 256, 0, stream>>>(cur);
    k_fill64<<<g256e, 256, 0, stream>>>(src, dst, cur, col);
    k_wt_all<<<(512 * 768 + 255) / 256, 256, 0, stream>>>(W1, W2, Wt1, Wt2);

    const int GM = (NN + 127) / 128;                 // 782
    k_gemm1_rs<<<GM * (DHID / 128), 256, 0, stream>>>(x, Wt1, cur, H1, NN);
    k_pull512<<<(NN + 3) / 4, 256, 0, stream>>>(cur, col, H1, b1, Hr);

    k_mfma_gemm<DOUT><<<GM * (DOUT / 128), 256, 0, stream>>>(Hr, Wt2, cur, H2, NN);
    k_pull256_lsm<<<(NN + 3) / 4, 256, 0, stream>>>(cur, col, H2, b2, out);
}

// Round 16
// 489.291 us; speedup vs baseline: 1.0830x; 1.0093x over previous
//
#include <hip/hip_runtime.h>
#include <hip/hip_bf16.h>

#define NN   100000
#define NE   800000
#define DIN  512
#define DHID 512
#define DOUT 256
#define CAP  64        // max neighbors stored per node (Poisson(8): P(>64)≈0)

typedef short  s16x8 __attribute__((ext_vector_type(8)));
typedef float  f32x4 __attribute__((ext_vector_type(4)));

__device__ __forceinline__ float bf2f(unsigned short b) {
    union { unsigned u; float f; } c; c.u = ((unsigned)b) << 16; return c.f;
}
__device__ __forceinline__ unsigned short f2bf(float f) {
    union { float f; unsigned u; } c; c.f = f;
    unsigned u = c.u;
    u += 0x7FFFu + ((u >> 16) & 1u);   // round-to-nearest-even
    return (unsigned short)(u >> 16);
}
__device__ __forceinline__ unsigned cvtpk_bf16(float lo, float hi) {
    unsigned r;
    asm("v_cvt_pk_bf16_f32 %0, %1, %2" : "=v"(r) : "v"(lo), "v"(hi));
    return r;                                  // {bf16(lo), bf16(hi)} RNE
}

__device__ __forceinline__ void gload_lds16(const void* g, void* l) {
    __builtin_amdgcn_global_load_lds(
        (const __attribute__((address_space(1))) void*)g,
        (__attribute__((address_space(3))) void*)l, 16, 0, 0);
}

// ---------- adjacency build (fixed-capacity, no scan) ----------
__global__ void k_zero(int* cur) {
    int i = blockIdx.x * 256 + threadIdx.x;
    if (i < NN) cur[i] = 0;
}
__global__ void k_fill64(const int* __restrict__ src, const int* __restrict__ dst,
                         int* __restrict__ cur, int* __restrict__ col)
{
    int i = blockIdx.x * 256 + threadIdx.x;
    if (i < NE) {
        const int d = dst[i];
        const int slot = atomicAdd(&cur[d], 1);
        if (slot < CAP) col[(size_t)d * CAP + slot] = src[i];
    }
}

// W1[512][512] -> Wt1[512][512] bf16 ; W2[512][256] -> Wt2[256][512] bf16
__global__ __launch_bounds__(256) void k_wt_all(
    const float* __restrict__ W1, const float* __restrict__ W2,
    unsigned short* __restrict__ Wt1, unsigned short* __restrict__ Wt2)
{
    const int idx = blockIdx.x * 256 + threadIdx.x;
    if (idx < 512 * 512) {
        const int k = idx >> 9, n = idx & 511;
        Wt1[n * 512 + k] = f2bf(W1[idx]);
    } else {
        const int r = idx - 512 * 512;
        if (r < 512 * 256) {
            const int k = r >> 8, n = r & 255;
            Wt2[n * 512 + k] = f2bf(W2[r]);
        }
    }
}

// ---------- GEMM1 (reg-staged f32 A, BK=64 twin buffers) ----------
// Two独立 [128][32] LDS buffers per operand (proven 64B-row conflict-free
// layout; 128B rows conflict — r7). Halves the barrier-drain events (8 iters
// vs 16). A-half stages kept sequential via sched_barrier(0) so in-flight
// stays 4x f32x4 (r14: 8 in flight -> 92 VGPR -> occupancy cliff).
__global__ __launch_bounds__(256) void k_gemm1_rs64(
    const float* __restrict__ A,            // [M][512] f32
    const unsigned short* __restrict__ Wt,  // [512][512] bf16
    const int* __restrict__ cur,
    unsigned short* __restrict__ Hb,        // [M][512] bf16 (h*dinv[m])
    int M)
{
    constexpr int K = 512, NC = 512, GN = NC / 128;
    __shared__ __align__(16) unsigned short As0[128 * 32];
    __shared__ __align__(16) unsigned short As1[128 * 32];
    __shared__ __align__(16) unsigned short Bs0[128 * 32];
    __shared__ __align__(16) unsigned short Bs1[128 * 32];

    const int GM  = (M + 127) >> 7;
    const int nwg = GM * GN;
    const int bid = blockIdx.x;
    const int q = nwg >> 3, r = nwg & 7;
    const int xcd = bid & 7, pos = bid >> 3;
    const int sbid = (xcd < r ? xcd * (q + 1) : r * (q + 1) + (xcd - r) * q) + pos;
    const int bm = (sbid / GN) * 128;
    const int bn = (sbid % GN) * 128;

    const int t    = threadIdx.x;
    const int lane = t & 63;
    const int wid  = t >> 6;
    const int wr = wid >> 1, wc = wid & 1;

    // A staging: thread t owns chunks c0=t and c1=t+256 (chunk = 8 elems)
    const int arow0 = t >> 2,          acp0 = t & 3;
    const int arow1 = (t + 256) >> 2,  acp1 = t & 3;
    int gr0 = bm + arow0; if (gr0 >= M) gr0 = M - 1;
    int gr1 = bm + arow1; if (gr1 >= M) gr1 = M - 1;
    const float* ga0 = A + (size_t)gr0 * K + acp0 * 8;
    const float* ga1 = A + (size_t)gr1 * K + acp1 * 8;
    const int woff0 = arow0 * 32 + (acp0 ^ ((arow0 >> 1) & 3)) * 8;
    const int woff1 = arow1 * 32 + (acp1 ^ ((arow1 >> 1) & 3)) * 8;

    f32x4 acc[4][4];
    #pragma unroll
    for (int i = 0; i < 4; ++i)
        #pragma unroll
        for (int j = 0; j < 4; ++j)
            acc[i][j] = (f32x4){0.f, 0.f, 0.f, 0.f};

    const int r16 = lane & 15;
    const int kc  = lane >> 4;

    for (int k0 = 0; k0 < K; k0 += 64) {    // dynamic loop — do not unroll
        // ---- B gload_lds for both halves ----
        #pragma unroll
        for (int i = 0; i < 2; ++i) {
            const int c   = i * 256 + t;
            const int row = c >> 2;
            const int cp  = c & 3;
            const int sc  = cp ^ ((row >> 1) & 3);
            const size_t bsrc = (size_t)(bn + row) * K;
            const size_t bdst = (size_t)(i * 256 + wid * 64) * 8;
            gload_lds16(Wt + bsrc + k0 + sc * 8,      &Bs0[bdst]);
            gload_lds16(Wt + bsrc + k0 + 32 + sc * 8, &Bs1[bdst]);
        }
        // ---- A half 0: load -> cvt -> write (4x f32x4 in flight) ----
        {
            const f32x4 a00 = *reinterpret_cast<const f32x4*>(ga0 + k0);
            const f32x4 a01 = *reinterpret_cast<const f32x4*>(ga0 + k0 + 4);
            const f32x4 a10 = *reinterpret_cast<const f32x4*>(ga1 + k0);
            const f32x4 a11 = *reinterpret_cast<const f32x4*>(ga1 + k0 + 4);
            uint4 p0, p1;
            p0.x = cvtpk_bf16(a00[0], a00[1]);  p0.y = cvtpk_bf16(a00[2], a00[3]);
            p0.z = cvtpk_bf16(a01[0], a01[1]);  p0.w = cvtpk_bf16(a01[2], a01[3]);
            p1.x = cvtpk_bf16(a10[0], a10[1]);  p1.y = cvtpk_bf16(a10[2], a10[3]);
            p1.z = cvtpk_bf16(a11[0], a11[1]);  p1.w = cvtpk_bf16(a11[2], a11[3]);
            *reinterpret_cast<uint4*>(&As0[woff0]) = p0;
            *reinterpret_cast<uint4*>(&As0[woff1]) = p1;
        }
        __builtin_amdgcn_sched_barrier(0);   // keep halves sequential (VGPR cap)
        // ---- A half 1 ----
        {
            const f32x4 a00 = *reinterpret_cast<const f32x4*>(ga0 + k0 + 32);
            const f32x4 a01 = *reinterpret_cast<const f32x4*>(ga0 + k0 + 36);
            const f32x4 a10 = *reinterpret_cast<const f32x4*>(ga1 + k0 + 32);
            const f32x4 a11 = *reinterpret_cast<const f32x4*>(ga1 + k0 + 36);
            uint4 p0, p1;
            p0.x = cvtpk_bf16(a00[0], a00[1]);  p0.y = cvtpk_bf16(a00[2], a00[3]);
            p0.z = cvtpk_bf16(a01[0], a01[1]);  p0.w = cvtpk_bf16(a01[2], a01[3]);
            p1.x = cvtpk_bf16(a10[0], a10[1]);  p1.y = cvtpk_bf16(a10[2], a10[3]);
            p1.z = cvtpk_bf16(a11[0], a11[1]);  p1.w = cvtpk_bf16(a11[2], a11[3]);
            *reinterpret_cast<uint4*>(&As1[woff0]) = p0;
            *reinterpret_cast<uint4*>(&As1[woff1]) = p1;
        }
        __syncthreads();     // one drain per 64-K (A writes + all gloads)

        s16x8 af[4], bf[4];
        #pragma unroll
        for (int i = 0; i < 4; ++i) {
            const int ra = wr * 64 + i * 16 + r16;
            af[i] = *reinterpret_cast<const s16x8*>(
                &As0[ra * 32 + ((kc ^ ((ra >> 1) & 3)) * 8)]);
            const int rb = wc * 64 + i * 16 + r16;
            bf[i] = *reinterpret_cast<const s16x8*>(
                &Bs0[rb * 32 + ((kc ^ ((rb >> 1) & 3)) * 8)]);
        }
        #pragma unroll
        for (int i = 0; i < 4; ++i)
            #pragma unroll
            for (int j = 0; j < 4; ++j)
                acc[i][j] = __builtin_amdgcn_mfma_f32_16x16x32_bf16(
                    af[i], bf[j], acc[i][j], 0, 0, 0);
        #pragma unroll
        for (int i = 0; i < 4; ++i) {
            const int ra = wr * 64 + i * 16 + r16;
            af[i] = *reinterpret_cast<const s16x8*>(
                &As1[ra * 32 + ((kc ^ ((ra >> 1) & 3)) * 8)]);
            const int rb = wc * 64 + i * 16 + r16;
            bf[i] = *reinterpret_cast<const s16x8*>(
                &Bs1[rb * 32 + ((kc ^ ((rb >> 1) & 3)) * 8)]);
        }
        #pragma unroll
        for (int i = 0; i < 4; ++i)
            #pragma unroll
            for (int j = 0; j < 4; ++j)
                acc[i][j] = __builtin_amdgcn_mfma_f32_16x16x32_bf16(
                    af[i], bf[j], acc[i][j], 0, 0, 0);
        __syncthreads();     // reads done before next iter's writes
    }

    #pragma unroll
    for (int i = 0; i < 4; ++i) {
        #pragma unroll
        for (int r2 = 0; r2 < 4; ++r2) {
            const int m = bm + wr * 64 + i * 16 + (lane >> 4) * 4 + r2;
            if (m >= M) continue;
            const float s = rsqrtf((float)cur[m] + 1.0f);
            #pragma unroll
            for (int j = 0; j < 4; ++j) {
                const int n = bn + wc * 64 + j * 16 + (lane & 15);
                Hb[(size_t)m * NC + n] = f2bf(acc[i][j][r2] * s);
            }
        }
    }
}

// ---------- GEMM2 (bf16 A via gload_lds, BK=64 twin buffers) ----------
template<int NC>
__global__ __launch_bounds__(256) void k_mfma_gemm64(
    const unsigned short* __restrict__ A,   // [M][512] bf16
    const unsigned short* __restrict__ Wt,  // [NC][512] bf16
    const int* __restrict__ cur,
    unsigned short* __restrict__ Hb,        // [M][NC] bf16  (h*dinv[m])
    int M)
{
    constexpr int K  = 512;
    constexpr int GN = NC / 128;
    __shared__ __align__(16) unsigned short As0[128 * 32];
    __shared__ __align__(16) unsigned short As1[128 * 32];
    __shared__ __align__(16) unsigned short Bs0[128 * 32];
    __shared__ __align__(16) unsigned short Bs1[128 * 32];

    const int GM  = (M + 127) >> 7;
    const int nwg = GM * GN;
    const int bid = blockIdx.x;
    const int q = nwg >> 3, r = nwg & 7;
    const int xcd = bid & 7, pos = bid >> 3;
    const int sbid = (xcd < r ? xcd * (q + 1) : r * (q + 1) + (xcd - r) * q) + pos;
    const int bm = (sbid / GN) * 128;
    const int bn = (sbid % GN) * 128;

    const int t    = threadIdx.x;
    const int lane = t & 63;
    const int wid  = t >> 6;
    const int wr = wid >> 1, wc = wid & 1;

    f32x4 acc[4][4];
    #pragma unroll
    for (int i = 0; i < 4; ++i)
        #pragma unroll
        for (int j = 0; j < 4; ++j)
            acc[i][j] = (f32x4){0.f, 0.f, 0.f, 0.f};

    const int r16 = lane & 15;
    const int kc  = lane >> 4;

    for (int k0 = 0; k0 < K; k0 += 64) {
        #pragma unroll
        for (int i = 0; i < 2; ++i) {
            const int c   = i * 256 + t;
            const int row = c >> 2;
            const int cp  = c & 3;
            const int sc  = cp ^ ((row >> 1) & 3);
            const int gr  = (bm + row < M) ? bm + row : M - 1;
            const size_t asrc = (size_t)gr * K;
            const size_t bsrc = (size_t)(bn + row) * K;
            const size_t dst  = (size_t)(i * 256 + wid * 64) * 8;
            gload_lds16(A  + asrc + k0 + sc * 8,      &As0[dst]);
            gload_lds16(A  + asrc + k0 + 32 + sc * 8, &As1[dst]);
            gload_lds16(Wt + bsrc + k0 + sc * 8,      &Bs0[dst]);
            gload_lds16(Wt + bsrc + k0 + 32 + sc * 8, &Bs1[dst]);
        }
        __syncthreads();

        s16x8 af[4], bf[4];
        #pragma unroll
        for (int i = 0; i < 4; ++i) {
            const int ra = wr * 64 + i * 16 + r16;
            af[i] = *reinterpret_cast<const s16x8*>(
                &As0[ra * 32 + ((kc ^ ((ra >> 1) & 3)) * 8)]);
            const int rb = wc * 64 + i * 16 + r16;
            bf[i] = *reinterpret_cast<const s16x8*>(
                &Bs0[rb * 32 + ((kc ^ ((rb >> 1) & 3)) * 8)]);
        }
        #pragma unroll
        for (int i = 0; i < 4; ++i)
            #pragma unroll
            for (int j = 0; j < 4; ++j)
                acc[i][j] = __builtin_amdgcn_mfma_f32_16x16x32_bf16(
                    af[i], bf[j], acc[i][j], 0, 0, 0);
        #pragma unroll
        for (int i = 0; i < 4; ++i) {
            const int ra = wr * 64 + i * 16 + r16;
            af[i] = *reinterpret_cast<const s16x8*>(
                &As1[ra * 32 + ((kc ^ ((ra >> 1) & 3)) * 8)]);
            const int rb = wc * 64 + i * 16 + r16;
            bf[i] = *reinterpret_cast<const s16x8*>(
                &Bs1[rb * 32 + ((kc ^ ((rb >> 1) & 3)) * 8)]);
        }
        #pragma unroll
        for (int i = 0; i < 4; ++i)
            #pragma unroll
            for (int j = 0; j < 4; ++j)
                acc[i][j] = __builtin_amdgcn_mfma_f32_16x16x32_bf16(
                    af[i], bf[j], acc[i][j], 0, 0, 0);
        __syncthreads();
    }

    #pragma unroll
    for (int i = 0; i < 4; ++i) {
        #pragma unroll
        for (int r2 = 0; r2 < 4; ++r2) {
            const int m = bm + wr * 64 + i * 16 + (lane >> 4) * 4 + r2;
            if (m >= M) continue;
            const float s = rsqrtf((float)cur[m] + 1.0f);
            #pragma unroll
            for (int j = 0; j < 4; ++j) {
                const int n = bn + wc * 64 + j * 16 + (lane & 15);
                Hb[(size_t)m * NC + n] = f2bf(acc[i][j][r2] * s);
            }
        }
    }
}

// ---------- pull, D=512: one wave per node, fused bias+relu, bf16 out ----------
__device__ __forceinline__ void add8(const uint4 u, float* a) {
    a[0] += bf2f((unsigned short)(u.x));  a[1] += bf2f((unsigned short)(u.x >> 16));
    a[2] += bf2f((unsigned short)(u.y));  a[3] += bf2f((unsigned short)(u.y >> 16));
    a[4] += bf2f((unsigned short)(u.z));  a[5] += bf2f((unsigned short)(u.z >> 16));
    a[6] += bf2f((unsigned short)(u.w));  a[7] += bf2f((unsigned short)(u.w >> 16));
}

__global__ __launch_bounds__(256) void k_pull512(
    const int* __restrict__ cur, const int* __restrict__ col,
    const unsigned short* __restrict__ H,
    const float* __restrict__ bias, unsigned short* __restrict__ Out)
{
    const int node = blockIdx.x * 4 + (threadIdx.x >> 6);
    if (node >= NN) return;
    const int lane = threadIdx.x & 63;

    float a[8] = {0.f, 0.f, 0.f, 0.f, 0.f, 0.f, 0.f, 0.f};
    add8(*reinterpret_cast<const uint4*>(H + (size_t)node * DHID + lane * 8), a);

    const int deg0 = cur[node];
    const int deg  = deg0 < CAP ? deg0 : CAP;
    const int* cl = col + (size_t)node * CAP;
    for (int e = 0; e < deg; ++e) {
        const int s = cl[e];
        add8(*reinterpret_cast<const uint4*>(H + (size_t)s * DHID + lane * 8), a);
    }

    const float sc = rsqrtf((float)deg0 + 1.0f);
    unsigned o[4];
    #pragma unroll
    for (int p = 0; p < 4; ++p) {
        float v0 = a[2 * p]     * sc + bias[lane * 8 + 2 * p];
        float v1 = a[2 * p + 1] * sc + bias[lane * 8 + 2 * p + 1];
        v0 = v0 > 0.f ? v0 : 0.f;
        v1 = v1 > 0.f ? v1 : 0.f;
        o[p] = (unsigned)f2bf(v0) | ((unsigned)f2bf(v1) << 16);
    }
    uint4 r = {o[0], o[1], o[2], o[3]};
    *reinterpret_cast<uint4*>(Out + (size_t)node * DHID + lane * 8) = r;
}

// ---------- pull, D=256: fused bias+log_softmax, f32 out ----------
__device__ __forceinline__ void add4(const uint2 u, float* a) {
    a[0] += bf2f((unsigned short)(u.x));  a[1] += bf2f((unsigned short)(u.x >> 16));
    a[2] += bf2f((unsigned short)(u.y));  a[3] += bf2f((unsigned short)(u.y >> 16));
}

__global__ __launch_bounds__(256) void k_pull256_lsm(
    const int* __restrict__ cur, const int* __restrict__ col,
    const unsigned short* __restrict__ H,
    const float* __restrict__ b2, float* __restrict__ out)
{
    const int node = blockIdx.x * 4 + (threadIdx.x >> 6);
    if (node >= NN) return;
    const int lane = threadIdx.x & 63;

    float a[4] = {0.f, 0.f, 0.f, 0.f};
    add4(*reinterpret_cast<const uint2*>(H + (size_t)node * DOUT + lane * 4), a);

    const int deg0 = cur[node];
    const int deg  = deg0 < CAP ? deg0 : CAP;
    const int* cl = col + (size_t)node * CAP;
    for (int e = 0; e < deg; ++e) {
        const int s = cl[e];
        add4(*reinterpret_cast<const uint2*>(H + (size_t)s * DOUT + lane * 4), a);
    }

    const float sc = rsqrtf((float)deg0 + 1.0f);
    float v0 = a[0] * sc + b2[lane * 4 + 0];
    float v1 = a[1] * sc + b2[lane * 4 + 1];
    float v2 = a[2] * sc + b2[lane * 4 + 2];
    float v3 = a[3] * sc + b2[lane * 4 + 3];

    float m = fmaxf(fmaxf(v0, v1), fmaxf(v2, v3));
    #pragma unroll
    for (int off = 32; off > 0; off >>= 1) m = fmaxf(m, __shfl_xor(m, off));
    float s = expf(v0 - m) + expf(v1 - m) + expf(v2 - m) + expf(v3 - m);
    #pragma unroll
    for (int off = 32; off > 0; off >>= 1) s += __shfl_xor(s, off);
    const float lse = m + logf(s);

    float4 rr = {v0 - lse, v1 - lse, v2 - lse, v3 - lse};
    *reinterpret_cast<float4*>(out + (size_t)node * DOUT + lane * 4) = rr;
}

extern "C" void kernel_launch(void* const* d_in, const int* in_sizes, int n_in,
                              void* d_out, int out_size, void* d_ws, size_t ws_size,
                              hipStream_t stream)
{
    const float* x  = (const float*)d_in[0];
    const int*   ei = (const int*)d_in[1];
    const float* W1 = (const float*)d_in[2];
    const float* b1 = (const float*)d_in[3];
    const float* W2 = (const float*)d_in[4];
    const float* b2 = (const float*)d_in[5];
    float* out = (float*)d_out;

    const int* src = ei;        // edge_index[0]
    const int* dst = ei + NE;   // edge_index[1]

    // workspace (high-water ~247 MiB):
    //   0.0MiB  cur   int[NN]
    //   1.0MiB  col   int[NN*64]             (25.6MB)
    //   28MiB   Wt1   bf16[512][512]
    //   29MiB   Wt2   bf16[256][512]
    //   32MiB   P: Hr bf16[NN][512]
    //   144MiB  Q: H1 bf16[NN][512] -> reused as H2 bf16[NN][256]
    char* ws = (char*)d_ws;
    int*   cur  = (int*)(ws);
    int*   col  = (int*)(ws + (size_t)(1 << 20));
    unsigned short* Wt1 = (unsigned short*)(ws + (size_t)28 * (1 << 20));
    unsigned short* Wt2 = (unsigned short*)(ws + (size_t)29 * (1 << 20));
    unsigned short* Hr  = (unsigned short*)(ws + (size_t)32  * (1 << 20));
    unsigned short* Q   = (unsigned short*)(ws + (size_t)144 * (1 << 20));
    unsigned short* H1 = Q, * H2 = Q;

    const int g256n = (NN + 255) / 256;
    const int g256e = (NE + 255) / 256;

    k_zero  <<<g256n, 256, 0, stream>>>(cur);
    k_fill64<<<g256e, 256, 0, stream>>>(src, dst, cur, col);
    k_wt_all<<<(512 * 768 + 255) / 256, 256, 0, stream>>>(W1, W2, Wt1, Wt2);

    const int GM = (NN + 127) / 128;                 // 782
    k_gemm1_rs64<<<GM * (DHID / 128), 256, 0, stream>>>(x, Wt1, cur, H1, NN);
    k_pull512<<<(NN + 3) / 4, 256, 0, stream>>>(cur, col, H1, b1, Hr);

    k_mfma_gemm64<DOUT><<<GM * (DOUT / 128), 256, 0, stream>>>(Hr, Wt2, cur, H2, NN);
    k_pull256_lsm<<<(NN + 3) / 4, 256, 0, stream>>>(cur, col, H2, b2, out);
}